// Round 10
// baseline (3811.058 us; speedup 1.0000x reference)
//
#include <hip/hip_runtime.h>

#define N_NODES 100000
#define M_PAD 100096   // 782*128; also GEMM tile padding
#define N_EDGES 3200000
#define DIM 512
#define SLOTS 80       // ELL capacity; max in-degree ~60 for Poisson(32)
#define NSLAB 32       // 512 / 16 cols
#define GRPS 782       // M_PAD / 128 node-groups per slab pass
#define NEG_SLOPE 0.01f

typedef _Float16 f16;
typedef _Float16 f16x8 __attribute__((ext_vector_type(8)));
typedef float f32x4 __attribute__((ext_vector_type(4)));

__device__ __forceinline__ void load_lds16(const void* g, void* l) {
  __builtin_amdgcn_global_load_lds(
      (const __attribute__((address_space(1))) void*)g,
      (__attribute__((address_space(3))) void*)l, 16, 0, 0);
}

// ---------------- graph preprocessing ----------------

// fused: out-degree histogram + ELL append (cnt_i doubles as in-degree)
__global__ void k_pre(const int* __restrict__ src, const int* __restrict__ dst,
                      int* __restrict__ cnt_o, int* __restrict__ cnt_i,
                      int* __restrict__ ell) {
  int e = blockIdx.x * blockDim.x + threadIdx.x;
  if (e < N_EDGES) {
    int s = src[e];
    atomicAdd(&cnt_o[s], 1);
    int d = dst[e];
    int p = atomicAdd(&cnt_i[d], 1);
    if (p < SLOTS) ell[(size_t)d * SLOTS + p] = s;
  }
}

__global__ void k_norms(const int* __restrict__ cnt_o, const int* __restrict__ cnt_i,
                        float* __restrict__ n_out, float* __restrict__ n_in) {
  int i = blockIdx.x * blockDim.x + threadIdx.x;
  if (i < N_NODES) {
    n_out[i] = rsqrtf((float)cnt_o[i] + 1.0f);
    n_in[i] = rsqrtf((float)cnt_i[i] + 1.0f);
  }
}

// degree-sorted node permutation (counting sort, 128 bins)
__global__ void k_dh(const int* __restrict__ cnt_i, int* __restrict__ bins) {
  int i = blockIdx.x * blockDim.x + threadIdx.x;
  if (i < N_NODES) atomicAdd(&bins[min(cnt_i[i], 127)], 1);
}
__global__ void k_dscan(const int* __restrict__ bins, int* __restrict__ bins2) {
  if (threadIdx.x == 0) {
    int s = 0;
    for (int i = 0; i < 128; i++) { int v = bins[i]; bins2[i] = s; s += v; }
  }
}
__global__ void k_dperm(const int* __restrict__ cnt_i, int* __restrict__ bins2,
                        int* __restrict__ perm) {
  int i = blockIdx.x * blockDim.x + threadIdx.x;
  if (i < N_NODES) {
    int pos = atomicAdd(&bins2[min(cnt_i[i], 127)], 1);
    perm[pos] = i;
  }
}

// W0/W1 [k][n] fp32 -> Wt [l][n][k] fp16 (transposed: B-fragment k contiguous)
__global__ void k_wt(const float* __restrict__ W0, const float* __restrict__ W1,
                     f16* __restrict__ Wt) {
  int idx = blockIdx.x * blockDim.x + threadIdx.x;
  int l = idx >> 18;          // DIM*DIM = 262144
  int r = idx & 262143;
  int n = r >> 9, k = r & 511;
  const float* W = (l == 0) ? W0 : W1;
  Wt[idx] = (f16)W[k * DIM + n];
}

// blocks 0..511: wt_vec[k] = W2[k,:] . pW ; block 512: c = b2.pW + pb
__global__ void k_wp(const float* __restrict__ W2, const float* __restrict__ b2,
                     const float* __restrict__ pW, const float* __restrict__ pb,
                     float* __restrict__ wt_vec, float* __restrict__ c_out) {
  int k = blockIdx.x, lane = threadIdx.x;
  if (k < DIM) {
    float s = 0.f;
    for (int n = lane; n < DIM; n += 64) s += W2[k * DIM + n] * pW[n];
#pragma unroll
    for (int off = 32; off; off >>= 1) s += __shfl_down(s, off, 64);
    if (lane == 0) wt_vec[k] = s;
  } else {
    float s = 0.f;
    for (int n = lane; n < DIM; n += 64) s += b2[n] * pW[n];
#pragma unroll
    for (int off = 32; off; off >>= 1) s += __shfl_down(s, off, 64);
    if (lane == 0) c_out[0] = s + pb[0];
  }
}

// ---------------- model ----------------
// Feature buffers use SLAB layout: F[slab s][node n][16 cols] fp16,
// element offset = (s*M_PAD + n)*16 + c.  One slab (3.2 MB) fits per-XCD L2.

// X = (concat(weight, emb[sig]) @ lin_W + lin_b) * n_out; wave per node
__global__ void k_feats(const float* __restrict__ weight, const int* __restrict__ sig,
                        const float* __restrict__ emb, const float* __restrict__ linW,
                        const float* __restrict__ linb, const float* __restrict__ n_out,
                        f16* __restrict__ Xs) {
  int wid = threadIdx.x >> 6, lane = threadIdx.x & 63;
  int node = blockIdx.x * 4 + wid;
  float w = weight[node];
  int sg = sig[node];
  float s0 = emb[sg * 2], s1 = emb[sg * 2 + 1];
  float no = n_out[node];
  int d0 = lane * 8;
  f16x8 v;
#pragma unroll
  for (int k = 0; k < 8; k++) {
    int d = d0 + k;
    float f = (w * linW[d] + s0 * linW[DIM + d] + s1 * linW[2 * DIM + d] + linb[d]) * no;
    v[k] = (f16)f;
  }
  // cols [lane*8, lane*8+8) -> slab lane>>1, half lane&1
  *(f16x8*)(Xs + ((size_t)(lane >> 1) * M_PAD + node) * 16 + (lane & 1) * 8) = v;
}

// Slab-pass SpMM: A[i,slab] = (X[i,slab] + sum X[src,slab]) * n_in[i].
// blockIdx.x = slab*GRPS + group (linear dispatch => slab phases time-grouped);
// 4 waves/block, wave = 32 nodes (degree-sorted via perm), lane-pair per node.
__global__ void k_spmm(const f16* __restrict__ Xs, f16* __restrict__ A,
                       const int* __restrict__ ell, const int* __restrict__ cnt_i,
                       const float* __restrict__ n_in, const int* __restrict__ perm) {
  const int wv = threadIdx.x >> 6, lane = threadIdx.x & 63;
  const int slab = blockIdx.x / GRPS;
  const int grp = blockIdx.x % GRPS;
  const int p = lane >> 1, h = lane & 1;
  const int slot = grp * 128 + wv * 32 + p;
  if (slot >= N_NODES) return;   // no barriers below
  const int node = perm[slot];
  const f16* Xsl = Xs + (size_t)slab * M_PAD * 16;
  float acc[8];
  {
    f16x8 sv = *(const f16x8*)(Xsl + (size_t)node * 16 + h * 8);
#pragma unroll
    for (int k = 0; k < 8; k++) acc[k] = (float)sv[k];
  }
  int deg = cnt_i[node];
  if (deg > SLOTS) deg = SLOTS;
  const int* erow = ell + (size_t)node * SLOTS;
  int j = 0;
  for (; j + 4 <= deg; j += 4) {
    int ix[4];
#pragma unroll
    for (int u = 0; u < 4; u++) ix[u] = __builtin_nontemporal_load(erow + j + u);
    f16x8 v[4];
#pragma unroll
    for (int u = 0; u < 4; u++) v[u] = *(const f16x8*)(Xsl + (size_t)ix[u] * 16 + h * 8);
#pragma unroll
    for (int u = 0; u < 4; u++)
#pragma unroll
      for (int k = 0; k < 8; k++) acc[k] += (float)v[u][k];
  }
  for (; j < deg; ++j) {
    int sn = __builtin_nontemporal_load(erow + j);
    f16x8 v = *(const f16x8*)(Xsl + (size_t)sn * 16 + h * 8);
#pragma unroll
    for (int k = 0; k < 8; k++) acc[k] += (float)v[k];
  }
  float ni = n_in[node];
  f16x8 o;
#pragma unroll
  for (int k = 0; k < 8; k++) o[k] = (f16)(acc[k] * ni);
  __builtin_nontemporal_store(o, (f16x8*)(A + ((size_t)slab * M_PAD + node) * 16 + h * 8));
}

// Y = leaky(A @ W + b) * n_out; A,Y in slab layout; LDS-staged 128x128 tile,
// BK=64, global_load_lds w16 w/ pre-swizzled source, XOR-swizzled ds_read.
__global__ __launch_bounds__(256) void k_gemm(const f16* __restrict__ A, const f16* __restrict__ Wt,
                                              const float* __restrict__ bias,
                                              const float* __restrict__ n_out,
                                              f16* __restrict__ Y) {
  __shared__ __align__(1024) char smem[32768];  // A tile [0,16K), W tile [16K,32K)
  const int tid = threadIdx.x;
  const int wid = tid >> 6, lane = tid & 63;
  const int lr = lane & 15, lk = lane >> 4;
  const int wr = wid >> 1, wc = wid & 1;
  const int cb = blockIdx.x * 128;  // N-tile
  const int rb = blockIdx.y * 128;  // M-tile
  const int ls = lane >> 3;         // row within 1KB chunk
  const int ss = lane & 7;          // 16B sub-chunk

  f32x4 acc[4][4];
#pragma unroll
  for (int i = 0; i < 4; i++)
#pragma unroll
    for (int j = 0; j < 4; j++) acc[i][j] = (f32x4){0.f, 0.f, 0.f, 0.f};

  for (int kb = 0; kb < DIM; kb += 64) {
#pragma unroll
    for (int i = 0; i < 4; i++) {
      int c = wid * 4 + i;
      int r = c * 8 + ls;
      int goff = (ss * 16) ^ ((r & 7) << 4);   // byte offset within 128B K-window
      int ch = goff >> 4;                       // 16B chunk 0..7 => cols kb+ch*8
      // A slab addressing: slab = kb/16 + ch/2, half = ch&1
      const char* ga = (const char*)A +
          (((size_t)((kb >> 4) + (ch >> 1)) * M_PAD + (rb + r)) * 16 + (ch & 1) * 8) * 2;
      load_lds16(ga, smem + c * 1024);
      const char* gw = (const char*)Wt + ((size_t)(cb + r) * DIM + kb) * 2 + goff;
      load_lds16(gw, smem + 16384 + c * 1024);
    }
    __syncthreads();
#pragma unroll
    for (int kk = 0; kk < 2; kk++) {
      f16x8 a[4], b[4];
#pragma unroll
      for (int fm = 0; fm < 4; fm++) {
        int row = wr * 64 + fm * 16 + lr;
        int byt = row * 128 + ((kk * 64 + lk * 16) ^ ((row & 7) << 4));
        a[fm] = *(const f16x8*)(smem + byt);
      }
#pragma unroll
      for (int fn = 0; fn < 4; fn++) {
        int row = wc * 64 + fn * 16 + lr;
        int byt = row * 128 + ((kk * 64 + lk * 16) ^ ((row & 7) << 4));
        b[fn] = *(const f16x8*)(smem + 16384 + byt);
      }
#pragma unroll
      for (int fm = 0; fm < 4; fm++)
#pragma unroll
        for (int fn = 0; fn < 4; fn++)
          acc[fm][fn] = __builtin_amdgcn_mfma_f32_16x16x32_f16(a[fm], b[fn], acc[fm][fn], 0, 0, 0);
    }
    __syncthreads();
  }

#pragma unroll
  for (int fn = 0; fn < 4; fn++) {
    int col = cb + wc * 64 + fn * 16 + lr;
    float bv = bias[col];
    size_t ybase = (size_t)(col >> 4) * M_PAD * 16 + (col & 15);
#pragma unroll
    for (int fm = 0; fm < 4; fm++) {
#pragma unroll
      for (int r = 0; r < 4; r++) {
        int row = rb + wr * 64 + fm * 16 + lk * 4 + r;
        if (row < N_NODES) {
          float v = acc[fm][fn][r] + bv;
          v = (v >= 0.f) ? v : NEG_SLOPE * v;   // LeakyReLU
          v *= n_out[row];                      // next layer's src-normalize
          Y[ybase + (size_t)row * 16] = (f16)v;
        }
      }
    }
  }
}

// y[i] = H[i,:] . wt_vec   (wave per node, slab layout)
__global__ void k_gemv(const f16* __restrict__ H, const float* __restrict__ wt_vec,
                       float* __restrict__ y) {
  int wid = threadIdx.x >> 6, lane = threadIdx.x & 63;
  int node = blockIdx.x * 4 + wid;
  int d0 = lane * 8;
  f16x8 v = *(const f16x8*)(H + ((size_t)(lane >> 1) * M_PAD + node) * 16 + (lane & 1) * 8);
  float s = 0.f;
#pragma unroll
  for (int k = 0; k < 8; k++) s += (float)v[k] * wt_vec[d0 + k];
#pragma unroll
  for (int off = 32; off; off >>= 1) s += __shfl_down(s, off, 64);
  if (lane == 0) y[node] = s;
}

// logits[i] = n_in[i]*(y[i] + sum y[src]) + c   (thread per node)
__global__ void k_sagg(const float* __restrict__ y, const int* __restrict__ ell,
                       const int* __restrict__ cnt_i, const float* __restrict__ n_in,
                       const float* __restrict__ c_out, float* __restrict__ out) {
  int i = blockIdx.x * blockDim.x + threadIdx.x;
  if (i >= N_NODES) return;
  int deg = cnt_i[i];
  if (deg > SLOTS) deg = SLOTS;
  const int* erow = ell + (size_t)i * SLOTS;
  float s = y[i];
  int j = 0;
  for (; j + 8 <= deg; j += 8) {
    int4 a = *(const int4*)(erow + j);
    int4 b = *(const int4*)(erow + j + 4);
    s += y[a.x] + y[a.y] + y[a.z] + y[a.w];
    s += y[b.x] + y[b.y] + y[b.z] + y[b.w];
  }
  for (; j < deg; ++j) s += y[erow[j]];
  out[i] = n_in[i] * s + c_out[0];
}

extern "C" void kernel_launch(void* const* d_in, const int* in_sizes, int n_in_cnt,
                              void* d_out, int out_size, void* d_ws, size_t ws_size,
                              hipStream_t stream) {
  const float* weight = (const float*)d_in[0];
  const int* sig = (const int*)d_in[1];
  const int* src = (const int*)d_in[2];
  const int* dst = (const int*)d_in[3];
  const float* emb = (const float*)d_in[4];
  const float* linW = (const float*)d_in[5];
  const float* linb = (const float*)d_in[6];
  const float* W0 = (const float*)d_in[7];
  const float* b0 = (const float*)d_in[8];
  const float* W1 = (const float*)d_in[9];
  const float* b1 = (const float*)d_in[10];
  const float* W2 = (const float*)d_in[11];
  const float* b2 = (const float*)d_in[12];
  const float* pW = (const float*)d_in[13];
  const float* pb = (const float*)d_in[14];
  float* out = (float*)d_out;

  char* ws = (char*)d_ws;
  size_t off = 0;
  auto alloc = [&](size_t bytes) {
    void* p = ws + off;
    off += (bytes + 255) & ~(size_t)255;
    return p;
  };
  int* cnt_o = (int*)alloc((size_t)N_NODES * 4);    // memset covers cnt_o..bins
  int* cnt_i = (int*)alloc((size_t)N_NODES * 4);
  int* bins = (int*)alloc(512);
  int* bins2 = (int*)alloc(512);
  float* n_out = (float*)alloc((size_t)N_NODES * 4);
  float* n_in = (float*)alloc((size_t)N_NODES * 4);
  int* perm = (int*)alloc((size_t)N_NODES * 4);
  int* ell = (int*)alloc((size_t)N_NODES * SLOTS * 4);
  f16* Wt = (f16*)alloc((size_t)2 * DIM * DIM * 2);
  float* wt_vec = (float*)alloc((size_t)DIM * 4);
  float* c_out = (float*)alloc(256);
  float* yv = (float*)alloc((size_t)N_NODES * 4);
  f16* B0 = (f16*)alloc((size_t)M_PAD * DIM * 2);
  f16* B1 = (f16*)alloc((size_t)M_PAD * DIM * 2);

  dim3 blk(256);
  hipMemsetAsync(cnt_o, 0, ((char*)bins + 512) - (char*)cnt_o, stream);
  k_pre<<<(N_EDGES + 255) / 256, blk, 0, stream>>>(src, dst, cnt_o, cnt_i, ell);
  k_norms<<<(N_NODES + 255) / 256, blk, 0, stream>>>(cnt_o, cnt_i, n_out, n_in);
  k_dh<<<(N_NODES + 255) / 256, blk, 0, stream>>>(cnt_i, bins);
  k_dscan<<<1, 64, 0, stream>>>(bins, bins2);
  k_dperm<<<(N_NODES + 255) / 256, blk, 0, stream>>>(cnt_i, bins2, perm);
  k_wt<<<2 * DIM * DIM / 256, blk, 0, stream>>>(W0, W1, Wt);
  k_wp<<<DIM + 1, 64, 0, stream>>>(W2, b2, pW, pb, wt_vec, c_out);
  k_feats<<<N_NODES / 4, blk, 0, stream>>>(weight, sig, emb, linW, linb, n_out, B0);

  dim3 sgrid(GRPS * NSLAB);
  dim3 ggrid(DIM / 128, M_PAD / 128);
  for (int l = 0; l < 2; l++) {
    k_spmm<<<sgrid, blk, 0, stream>>>(B0, B1, ell, cnt_i, n_in, perm);
    const float* bl = (l == 0) ? b0 : b1;
    k_gemm<<<ggrid, blk, 0, stream>>>(B1, Wt + (size_t)l * DIM * DIM, bl, n_out, B0);
  }
  k_gemv<<<N_NODES / 4, blk, 0, stream>>>(B0, wt_vec, yv);
  k_sagg<<<(N_NODES + 255) / 256, blk, 0, stream>>>(yv, ell, cnt_i, n_in, c_out, out);
}

// Round 11
// 1651.287 us; speedup vs baseline: 2.3079x; 2.3079x over previous
//
#include <hip/hip_runtime.h>

#define N_NODES 100000
#define M_PAD 100096   // 782 * 128, GEMM-tile-padded row count
#define N_EDGES 3200000
#define DIM 512
#define SLOTS 80       // ELL capacity; max in-degree ~60 for Poisson(32)
#define NEG_SLOPE 0.01f

typedef _Float16 f16;
typedef _Float16 f16x8 __attribute__((ext_vector_type(8)));
typedef float f32x4 __attribute__((ext_vector_type(4)));

__device__ __forceinline__ void load_lds16(const void* g, void* l) {
  __builtin_amdgcn_global_load_lds(
      (const __attribute__((address_space(1))) void*)g,
      (__attribute__((address_space(3))) void*)l, 16, 0, 0);
}

// ---------------- graph preprocessing ----------------

// fused: out-degree histogram + ELL append (cnt_i doubles as in-degree)
__global__ void k_pre(const int* __restrict__ src, const int* __restrict__ dst,
                      int* __restrict__ cnt_o, int* __restrict__ cnt_i,
                      int* __restrict__ ell) {
  int e = blockIdx.x * blockDim.x + threadIdx.x;
  if (e < N_EDGES) {
    int s = src[e];
    atomicAdd(&cnt_o[s], 1);
    int d = dst[e];
    int p = atomicAdd(&cnt_i[d], 1);
    if (p < SLOTS) ell[(size_t)d * SLOTS + p] = s;
  }
}

__global__ void k_norms(const int* __restrict__ cnt_o, const int* __restrict__ cnt_i,
                        float* __restrict__ n_out, float* __restrict__ n_in) {
  int i = blockIdx.x * blockDim.x + threadIdx.x;
  if (i < N_NODES) {
    n_out[i] = rsqrtf((float)cnt_o[i] + 1.0f);
    n_in[i] = rsqrtf((float)cnt_i[i] + 1.0f);
  }
}

// W0/W1 [k][n] fp32 -> Wt [l][n][k] fp16 (transposed: B-fragment k contiguous)
__global__ void k_wt(const float* __restrict__ W0, const float* __restrict__ W1,
                     f16* __restrict__ Wt) {
  int idx = blockIdx.x * blockDim.x + threadIdx.x;
  int l = idx >> 18;          // DIM*DIM = 262144
  int r = idx & 262143;
  int n = r >> 9, k = r & 511;
  const float* W = (l == 0) ? W0 : W1;
  Wt[idx] = (f16)W[k * DIM + n];
}

// blocks 0..511: wt_vec[k] = W2[k,:] . pW ; block 512: c = b2.pW + pb
__global__ void k_wp(const float* __restrict__ W2, const float* __restrict__ b2,
                     const float* __restrict__ pW, const float* __restrict__ pb,
                     float* __restrict__ wt_vec, float* __restrict__ c_out) {
  int k = blockIdx.x, lane = threadIdx.x;
  if (k < DIM) {
    float s = 0.f;
    for (int n = lane; n < DIM; n += 64) s += W2[k * DIM + n] * pW[n];
#pragma unroll
    for (int off = 32; off; off >>= 1) s += __shfl_down(s, off, 64);
    if (lane == 0) wt_vec[k] = s;
  } else {
    float s = 0.f;
    for (int n = lane; n < DIM; n += 64) s += b2[n] * pW[n];
#pragma unroll
    for (int off = 32; off; off >>= 1) s += __shfl_down(s, off, 64);
    if (lane == 0) c_out[0] = s + pb[0];
  }
}

// ---------------- model ----------------

// X = (concat(weight, emb[sig]) @ lin_W + lin_b) * n_out  (fp16), wave per node
__global__ void k_feats(const float* __restrict__ weight, const int* __restrict__ sig,
                        const float* __restrict__ emb, const float* __restrict__ linW,
                        const float* __restrict__ linb, const float* __restrict__ n_out,
                        f16* __restrict__ Xs) {
  int wid = threadIdx.x >> 6, lane = threadIdx.x & 63;
  int node = blockIdx.x * 4 + wid;
  float w = weight[node];
  int sg = sig[node];
  float s0 = emb[sg * 2], s1 = emb[sg * 2 + 1];
  float no = n_out[node];
  int d0 = lane * 8;
  f16x8 v;
#pragma unroll
  for (int k = 0; k < 8; k++) {
    int d = d0 + k;
    float f = (w * linW[d] + s0 * linW[DIM + d] + s1 * linW[2 * DIM + d] + linb[d]) * no;
    v[k] = (f16)f;
  }
  *(f16x8*)(Xs + (size_t)node * DIM + d0) = v;
}

// A[i] = (X[i] + sum_{e: dst=i} X[src_e]) * n_in[i]
// wave per node (512 cols, 16B/lane); ELL gather unrolled 8x.
__global__ void k_spmm(const f16* __restrict__ Xs, f16* __restrict__ A,
                       const int* __restrict__ ell, const int* __restrict__ cnt_i,
                       const float* __restrict__ n_in) {
  int wid = threadIdx.x >> 6, lane = threadIdx.x & 63;
  int node = blockIdx.x * 4 + wid;
  int d0 = lane * 8;
  float acc[8];
  {
    f16x8 v = *(const f16x8*)(Xs + (size_t)node * DIM + d0);
#pragma unroll
    for (int k = 0; k < 8; k++) acc[k] = (float)v[k];
  }
  int deg = cnt_i[node];
  if (deg > SLOTS) deg = SLOTS;
  const int* erow = ell + (size_t)node * SLOTS;
  const f16* base = Xs + d0;
  int j = 0;
  for (; j + 8 <= deg; j += 8) {
    int ix[8];
#pragma unroll
    for (int u = 0; u < 8; u++) ix[u] = erow[j + u];
    f16x8 v[8];
#pragma unroll
    for (int u = 0; u < 8; u++) v[u] = *(const f16x8*)(base + (size_t)ix[u] * DIM);
#pragma unroll
    for (int u = 0; u < 8; u++)
#pragma unroll
      for (int k = 0; k < 8; k++) acc[k] += (float)v[u][k];
  }
  for (; j < deg; ++j) {
    int sn = erow[j];
    f16x8 v = *(const f16x8*)(base + (size_t)sn * DIM);
#pragma unroll
    for (int k = 0; k < 8; k++) acc[k] += (float)v[k];
  }
  float ni = n_in[node];
  f16x8 o;
#pragma unroll
  for (int k = 0; k < 8; k++) o[k] = (f16)(acc[k] * ni);
  __builtin_nontemporal_store(o, (f16x8*)(A + (size_t)node * DIM + d0));
}

// Y = leaky(A @ W + b) * n_out  (yv == nullptr path, feeds next spmm), or
// yv[row] += (leaky(A @ W + b) . wt_vec) * n_out  (fused final GEMV, no Y write).
// LDS-staged 128x128 tile, BK=64, global_load_lds w16 w/ pre-swizzled source,
// XOR-swizzled ds_read. 256 thr = 4 waves (2x2), wave tile 64x64.
__global__ __launch_bounds__(256) void k_gemm(const f16* __restrict__ A, const f16* __restrict__ Wt,
                                              const float* __restrict__ bias,
                                              const float* __restrict__ n_out,
                                              f16* __restrict__ Y,
                                              const float* __restrict__ wt_vec,
                                              float* __restrict__ yv) {
  __shared__ __align__(1024) char smem[32768];  // A tile [0,16K), W tile [16K,32K)
  __shared__ float yred[128];
  const int tid = threadIdx.x;
  const int wid = tid >> 6, lane = tid & 63;
  const int lr = lane & 15, lk = lane >> 4;
  const int wr = wid >> 1, wc = wid & 1;
  const int cb = blockIdx.x * 128;  // N-tile
  const int rb = blockIdx.y * 128;  // M-tile
  const int ls = lane >> 3;         // row within 1KB chunk (8 rows/chunk)
  const int ss = lane & 7;          // 16B sub-chunk within row-half

  f32x4 acc[4][4];
#pragma unroll
  for (int i = 0; i < 4; i++)
#pragma unroll
    for (int j = 0; j < 4; j++) acc[i][j] = (f32x4){0.f, 0.f, 0.f, 0.f};

  for (int kb = 0; kb < DIM; kb += 64) {
#pragma unroll
    for (int i = 0; i < 4; i++) {
      int c = wid * 4 + i;
      int r = c * 8 + ls;
      int goff = (ss * 16) ^ ((r & 7) << 4);
      const char* ga = (const char*)A + ((size_t)(rb + r) * DIM + kb) * 2 + goff;
      load_lds16(ga, smem + c * 1024);
      const char* gw = (const char*)Wt + ((size_t)(cb + r) * DIM + kb) * 2 + goff;
      load_lds16(gw, smem + 16384 + c * 1024);
    }
    __syncthreads();
#pragma unroll
    for (int kk = 0; kk < 2; kk++) {
      f16x8 a[4], b[4];
#pragma unroll
      for (int fm = 0; fm < 4; fm++) {
        int row = wr * 64 + fm * 16 + lr;
        int byt = row * 128 + ((kk * 64 + lk * 16) ^ ((row & 7) << 4));
        a[fm] = *(const f16x8*)(smem + byt);
      }
#pragma unroll
      for (int fn = 0; fn < 4; fn++) {
        int row = wc * 64 + fn * 16 + lr;
        int byt = row * 128 + ((kk * 64 + lk * 16) ^ ((row & 7) << 4));
        b[fn] = *(const f16x8*)(smem + 16384 + byt);
      }
#pragma unroll
      for (int fm = 0; fm < 4; fm++)
#pragma unroll
        for (int fn = 0; fn < 4; fn++)
          acc[fm][fn] = __builtin_amdgcn_mfma_f32_16x16x32_f16(a[fm], b[fn], acc[fm][fn], 0, 0, 0);
    }
    __syncthreads();
  }

  if (yv == nullptr) {
    // standard epilogue: Y = n_out * leaky(acc + b)
#pragma unroll
    for (int fn = 0; fn < 4; fn++) {
      int col = cb + wc * 64 + fn * 16 + lr;
      float bv = bias[col];
#pragma unroll
      for (int fm = 0; fm < 4; fm++) {
#pragma unroll
        for (int r = 0; r < 4; r++) {
          int row = rb + wr * 64 + fm * 16 + lk * 4 + r;
          if (row < N_NODES) {
            float v = acc[fm][fn][r] + bv;
            v = (v >= 0.f) ? v : NEG_SLOPE * v;   // LeakyReLU
            v *= n_out[row];                      // next layer's src-normalize
            Y[(size_t)row * DIM + col] = (f16)v;
          }
        }
      }
    }
  } else {
    // fused GEMV epilogue: yv[row] += n_out[row] * sum_col leaky(acc+b)*wt_vec[col]
    if (tid < 128) yred[tid] = 0.f;
    __syncthreads();
#pragma unroll
    for (int fm = 0; fm < 4; fm++) {
#pragma unroll
      for (int r = 0; r < 4; r++) {
        int rloc = wr * 64 + fm * 16 + lk * 4 + r;
        int row = rb + rloc;
        float p = 0.f;
#pragma unroll
        for (int fn = 0; fn < 4; fn++) {
          int col = cb + wc * 64 + fn * 16 + lr;
          float v = acc[fm][fn][r] + bias[col];
          v = (v >= 0.f) ? v : NEG_SLOPE * v;
          p += v * wt_vec[col];
        }
        if (row < N_NODES) atomicAdd(&yred[rloc], p * n_out[row]);
      }
    }
    __syncthreads();
    if (tid < 128) {
      int row = rb + tid;
      if (row < N_NODES) atomicAdd(&yv[row], yred[tid]);
    }
  }
}

// logits[i] = n_in[i]*(y[i] + sum y[src]) + c   (thread per node)
__global__ void k_sagg(const float* __restrict__ y, const int* __restrict__ ell,
                       const int* __restrict__ cnt_i, const float* __restrict__ n_in,
                       const float* __restrict__ c_out, float* __restrict__ out) {
  int i = blockIdx.x * blockDim.x + threadIdx.x;
  if (i >= N_NODES) return;
  int deg = cnt_i[i];
  if (deg > SLOTS) deg = SLOTS;
  const int* erow = ell + (size_t)i * SLOTS;
  float s = y[i];
  int j = 0;
  for (; j + 8 <= deg; j += 8) {
    int4 a = *(const int4*)(erow + j);
    int4 b = *(const int4*)(erow + j + 4);
    s += y[a.x] + y[a.y] + y[a.z] + y[a.w];
    s += y[b.x] + y[b.y] + y[b.z] + y[b.w];
  }
  for (; j < deg; ++j) s += y[erow[j]];
  out[i] = n_in[i] * s + c_out[0];
}

extern "C" void kernel_launch(void* const* d_in, const int* in_sizes, int n_in_cnt,
                              void* d_out, int out_size, void* d_ws, size_t ws_size,
                              hipStream_t stream) {
  const float* weight = (const float*)d_in[0];
  const int* sig = (const int*)d_in[1];
  const int* src = (const int*)d_in[2];
  const int* dst = (const int*)d_in[3];
  const float* emb = (const float*)d_in[4];
  const float* linW = (const float*)d_in[5];
  const float* linb = (const float*)d_in[6];
  const float* W0 = (const float*)d_in[7];
  const float* b0 = (const float*)d_in[8];
  const float* W1 = (const float*)d_in[9];
  const float* b1 = (const float*)d_in[10];
  const float* W2 = (const float*)d_in[11];
  const float* b2 = (const float*)d_in[12];
  const float* pW = (const float*)d_in[13];
  const float* pb = (const float*)d_in[14];
  float* out = (float*)d_out;

  char* ws = (char*)d_ws;
  size_t off = 0;
  auto alloc = [&](size_t bytes) {
    void* p = ws + off;
    off += (bytes + 255) & ~(size_t)255;
    return p;
  };
  // cnt_o, cnt_i, yv contiguous: one memset zeroes all three
  int* cnt_o = (int*)alloc((size_t)N_NODES * 4);
  int* cnt_i = (int*)alloc((size_t)N_NODES * 4);
  float* yv = (float*)alloc((size_t)N_NODES * 4);
  float* n_out = (float*)alloc((size_t)N_NODES * 4);
  float* n_in = (float*)alloc((size_t)N_NODES * 4);
  int* ell = (int*)alloc((size_t)N_NODES * SLOTS * 4);
  f16* Wt = (f16*)alloc((size_t)2 * DIM * DIM * 2);
  float* wt_vec = (float*)alloc((size_t)DIM * 4);
  float* c_out = (float*)alloc(256);
  f16* B0 = (f16*)alloc((size_t)M_PAD * DIM * 2);
  f16* B1 = (f16*)alloc((size_t)M_PAD * DIM * 2);

  dim3 blk(256);
  hipMemsetAsync(cnt_o, 0, (char*)n_out - (char*)cnt_o, stream);  // cnt_o+cnt_i+yv
  k_pre<<<(N_EDGES + 255) / 256, blk, 0, stream>>>(src, dst, cnt_o, cnt_i, ell);
  k_norms<<<(N_NODES + 255) / 256, blk, 0, stream>>>(cnt_o, cnt_i, n_out, n_in);
  k_wt<<<2 * DIM * DIM / 256, blk, 0, stream>>>(W0, W1, Wt);
  k_wp<<<DIM + 1, 64, 0, stream>>>(W2, b2, pW, pb, wt_vec, c_out);
  k_feats<<<N_NODES / 4, blk, 0, stream>>>(weight, sig, emb, linW, linb, n_out, B0);

  dim3 ggrid(DIM / 128, M_PAD / 128);
  // layer 1
  k_spmm<<<N_NODES / 4, blk, 0, stream>>>(B0, B1, ell, cnt_i, n_in);
  k_gemm<<<ggrid, blk, 0, stream>>>(B1, Wt, b0, n_out, B0, nullptr, nullptr);
  // layer 2 + fused final GEMV (layer-3 collapse)
  k_spmm<<<N_NODES / 4, blk, 0, stream>>>(B0, B1, ell, cnt_i, n_in);
  k_gemm<<<ggrid, blk, 0, stream>>>(B1, Wt + (size_t)DIM * DIM, b1, n_out, nullptr, wt_vec, yv);
  // layer-3 scalar aggregation
  k_sagg<<<(N_NODES + 255) / 256, blk, 0, stream>>>(yv, ell, cnt_i, n_in, c_out, out);
}

// Round 12
// 1640.429 us; speedup vs baseline: 2.3232x; 1.0066x over previous
//
#include <hip/hip_runtime.h>

#define N_NODES 100000
#define M_PAD 100096   // 782 * 128, GEMM-tile-padded row count
#define N_EDGES 3200000
#define DIM 512
#define SLOTS 80       // ELL capacity; max in-degree ~60 for Poisson(32)
#define NEG_SLOPE 0.01f

// k_setup block partition
#define B_PRE 12500            // N_EDGES / 256
#define B_WT (B_PRE + 2048)    // 2*DIM*DIM / 256
#define B_WP (B_WT + 129)      // 516 wave-tasks / 4
#define B_FEAT (B_WP + 25000)  // N_NODES / 4

typedef _Float16 f16;
typedef _Float16 f16x8 __attribute__((ext_vector_type(8)));
typedef float f32x4 __attribute__((ext_vector_type(4)));

__device__ __forceinline__ void load_lds16(const void* g, void* l) {
  __builtin_amdgcn_global_load_lds(
      (const __attribute__((address_space(1))) void*)g,
      (__attribute__((address_space(3))) void*)l, 16, 0, 0);
}

// ---------------- fused setup ----------------
// blocks [0,B_PRE):   edge atomics (out-deg histogram + ELL append)
// blocks [B_PRE,B_WT): W0/W1 -> Wt fp16 transposed
// blocks [B_WT,B_WP):  wt_vec = W2 . pW ; c = b2.pW + pb   (wave per k)
// blocks [B_WP,B_FEAT): X = concat(weight, emb[sig]) @ lin_W + lin_b (UNSCALED)
__global__ void k_setup(const int* __restrict__ src, const int* __restrict__ dst,
                        int* __restrict__ cnt_o, int* __restrict__ cnt_i,
                        int* __restrict__ ell,
                        const float* __restrict__ W0, const float* __restrict__ W1,
                        f16* __restrict__ Wt,
                        const float* __restrict__ W2, const float* __restrict__ b2,
                        const float* __restrict__ pW, const float* __restrict__ pb,
                        float* __restrict__ wt_vec, float* __restrict__ c_out,
                        const float* __restrict__ weight, const int* __restrict__ sig,
                        const float* __restrict__ emb, const float* __restrict__ linW,
                        const float* __restrict__ linb, f16* __restrict__ Xs) {
  const int bid = blockIdx.x;
  const int tid = threadIdx.x;
  if (bid < B_PRE) {
    int e = bid * 256 + tid;            // B_PRE*256 == N_EDGES exactly
    int s = src[e];
    atomicAdd(&cnt_o[s], 1);
    int d = dst[e];
    int p = atomicAdd(&cnt_i[d], 1);
    if (p < SLOTS) ell[(size_t)d * SLOTS + p] = s;
  } else if (bid < B_WT) {
    int idx = (bid - B_PRE) * 256 + tid;
    int l = idx >> 18;                  // DIM*DIM = 262144
    int r = idx & 262143;
    int n = r >> 9, k = r & 511;
    const float* W = l ? W1 : W0;
    Wt[idx] = (f16)W[k * DIM + n];
  } else if (bid < B_WP) {
    int wid = tid >> 6, lane = tid & 63;
    int t = (bid - B_WT) * 4 + wid;     // 0..515
    if (t < DIM) {
      float s = 0.f;
#pragma unroll
      for (int n = 0; n < DIM; n += 64) s += W2[t * DIM + n + lane] * pW[n + lane];
#pragma unroll
      for (int off = 32; off; off >>= 1) s += __shfl_down(s, off, 64);
      if (lane == 0) wt_vec[t] = s;
    } else if (t == DIM) {
      float s = 0.f;
#pragma unroll
      for (int n = 0; n < DIM; n += 64) s += b2[n + lane] * pW[n + lane];
#pragma unroll
      for (int off = 32; off; off >>= 1) s += __shfl_down(s, off, 64);
      if (lane == 0) c_out[0] = s + pb[0];
    }
  } else {
    int wid = tid >> 6, lane = tid & 63;
    int node = (bid - B_WP) * 4 + wid;
    float w = weight[node];
    int sg = sig[node];
    float s0 = emb[sg * 2], s1 = emb[sg * 2 + 1];
    int d0 = lane * 8;
    f16x8 v;
#pragma unroll
    for (int k = 0; k < 8; k++) {
      int d = d0 + k;
      v[k] = (f16)(w * linW[d] + s0 * linW[DIM + d] + s1 * linW[2 * DIM + d] + linb[d]);
    }
    *(f16x8*)(Xs + (size_t)node * DIM + d0) = v;
  }
}

__global__ void k_norms(const int* __restrict__ cnt_o, const int* __restrict__ cnt_i,
                        float* __restrict__ n_out, float* __restrict__ n_in) {
  int i = blockIdx.x * blockDim.x + threadIdx.x;
  if (i < N_NODES) {
    n_out[i] = rsqrtf((float)cnt_o[i] + 1.0f);
    n_in[i] = rsqrtf((float)cnt_i[i] + 1.0f);
  }
}

// ---------------- model ----------------
// Feature buffers hold UNSCALED h; the n_out[src] pre-scale is applied inside
// spmm (per-source fp32 fma) and in the fused-GEMV epilogue.

// A[i] = n_in[i] * (n_out[i]*X[i] + sum_{e: dst=i} n_out[src]*X[src_e])
// wave per node (512 cols, 16B/lane); ELL gather unrolled 8x.
__global__ void k_spmm(const f16* __restrict__ Xs, f16* __restrict__ A,
                       const int* __restrict__ ell, const int* __restrict__ cnt_i,
                       const float* __restrict__ n_in, const float* __restrict__ n_out) {
  int wid = threadIdx.x >> 6, lane = threadIdx.x & 63;
  int node = blockIdx.x * 4 + wid;
  int d0 = lane * 8;
  float acc[8];
  {
    f16x8 v = *(const f16x8*)(Xs + (size_t)node * DIM + d0);
    float no = n_out[node];
#pragma unroll
    for (int k = 0; k < 8; k++) acc[k] = no * (float)v[k];
  }
  int deg = cnt_i[node];
  if (deg > SLOTS) deg = SLOTS;
  const int* erow = ell + (size_t)node * SLOTS;
  const f16* base = Xs + d0;
  int j = 0;
  for (; j + 8 <= deg; j += 8) {
    int ix[8];
#pragma unroll
    for (int u = 0; u < 8; u++) ix[u] = erow[j + u];
    float sc[8];
#pragma unroll
    for (int u = 0; u < 8; u++) sc[u] = n_out[ix[u]];
    f16x8 v[8];
#pragma unroll
    for (int u = 0; u < 8; u++) v[u] = *(const f16x8*)(base + (size_t)ix[u] * DIM);
#pragma unroll
    for (int u = 0; u < 8; u++)
#pragma unroll
      for (int k = 0; k < 8; k++) acc[k] += sc[u] * (float)v[u][k];
  }
  for (; j < deg; ++j) {
    int sn = erow[j];
    float sc = n_out[sn];
    f16x8 v = *(const f16x8*)(base + (size_t)sn * DIM);
#pragma unroll
    for (int k = 0; k < 8; k++) acc[k] += sc * (float)v[k];
  }
  float ni = n_in[node];
  f16x8 o;
#pragma unroll
  for (int k = 0; k < 8; k++) o[k] = (f16)(acc[k] * ni);
  __builtin_nontemporal_store(o, (f16x8*)(A + (size_t)node * DIM + d0));
}

// Y = leaky(A @ W + b)  (yv == nullptr path, UNSCALED, feeds next spmm), or
// yv[row] += (leaky(A @ W + b) . wt_vec) * n_out[row]  (fused final GEMV).
// LDS-staged 128x128 tile, BK=64, global_load_lds w16 w/ pre-swizzled source,
// XOR-swizzled ds_read. 256 thr = 4 waves (2x2), wave tile 64x64.
__global__ __launch_bounds__(256) void k_gemm(const f16* __restrict__ A, const f16* __restrict__ Wt,
                                              const float* __restrict__ bias,
                                              const float* __restrict__ n_out,
                                              f16* __restrict__ Y,
                                              const float* __restrict__ wt_vec,
                                              float* __restrict__ yv) {
  __shared__ __align__(1024) char smem[32768];  // A tile [0,16K), W tile [16K,32K)
  __shared__ float yred[128];
  const int tid = threadIdx.x;
  const int wid = tid >> 6, lane = tid & 63;
  const int lr = lane & 15, lk = lane >> 4;
  const int wr = wid >> 1, wc = wid & 1;
  const int cb = blockIdx.x * 128;  // N-tile
  const int rb = blockIdx.y * 128;  // M-tile
  const int ls = lane >> 3;         // row within 1KB chunk (8 rows/chunk)
  const int ss = lane & 7;          // 16B sub-chunk within row-half

  f32x4 acc[4][4];
#pragma unroll
  for (int i = 0; i < 4; i++)
#pragma unroll
    for (int j = 0; j < 4; j++) acc[i][j] = (f32x4){0.f, 0.f, 0.f, 0.f};

  for (int kb = 0; kb < DIM; kb += 64) {
#pragma unroll
    for (int i = 0; i < 4; i++) {
      int c = wid * 4 + i;
      int r = c * 8 + ls;
      int goff = (ss * 16) ^ ((r & 7) << 4);
      const char* ga = (const char*)A + ((size_t)(rb + r) * DIM + kb) * 2 + goff;
      load_lds16(ga, smem + c * 1024);
      const char* gw = (const char*)Wt + ((size_t)(cb + r) * DIM + kb) * 2 + goff;
      load_lds16(gw, smem + 16384 + c * 1024);
    }
    __syncthreads();
#pragma unroll
    for (int kk = 0; kk < 2; kk++) {
      f16x8 a[4], b[4];
#pragma unroll
      for (int fm = 0; fm < 4; fm++) {
        int row = wr * 64 + fm * 16 + lr;
        int byt = row * 128 + ((kk * 64 + lk * 16) ^ ((row & 7) << 4));
        a[fm] = *(const f16x8*)(smem + byt);
      }
#pragma unroll
      for (int fn = 0; fn < 4; fn++) {
        int row = wc * 64 + fn * 16 + lr;
        int byt = row * 128 + ((kk * 64 + lk * 16) ^ ((row & 7) << 4));
        b[fn] = *(const f16x8*)(smem + 16384 + byt);
      }
#pragma unroll
      for (int fm = 0; fm < 4; fm++)
#pragma unroll
        for (int fn = 0; fn < 4; fn++)
          acc[fm][fn] = __builtin_amdgcn_mfma_f32_16x16x32_f16(a[fm], b[fn], acc[fm][fn], 0, 0, 0);
    }
    __syncthreads();
  }

  if (yv == nullptr) {
    // standard epilogue: Y = leaky(acc + b)  (unscaled)
#pragma unroll
    for (int fn = 0; fn < 4; fn++) {
      int col = cb + wc * 64 + fn * 16 + lr;
      float bv = bias[col];
#pragma unroll
      for (int fm = 0; fm < 4; fm++) {
#pragma unroll
        for (int r = 0; r < 4; r++) {
          int row = rb + wr * 64 + fm * 16 + lk * 4 + r;
          if (row < N_NODES) {
            float v = acc[fm][fn][r] + bv;
            v = (v >= 0.f) ? v : NEG_SLOPE * v;   // LeakyReLU
            Y[(size_t)row * DIM + col] = (f16)v;
          }
        }
      }
    }
  } else {
    // fused GEMV epilogue: yv[row] += n_out[row] * sum_col leaky(acc+b)*wt_vec[col]
    if (tid < 128) yred[tid] = 0.f;
    __syncthreads();
#pragma unroll
    for (int fm = 0; fm < 4; fm++) {
#pragma unroll
      for (int r = 0; r < 4; r++) {
        int rloc = wr * 64 + fm * 16 + lk * 4 + r;
        int row = rb + rloc;
        float p = 0.f;
#pragma unroll
        for (int fn = 0; fn < 4; fn++) {
          int col = cb + wc * 64 + fn * 16 + lr;
          float v = acc[fm][fn][r] + bias[col];
          v = (v >= 0.f) ? v : NEG_SLOPE * v;
          p += v * wt_vec[col];
        }
        if (row < N_NODES) atomicAdd(&yred[rloc], p * n_out[row]);
      }
    }
    __syncthreads();
    if (tid < 128) {
      int row = rb + tid;
      if (row < N_NODES) atomicAdd(&yv[row], yred[tid]);
    }
  }
}

// logits[i] = n_in[i]*(y[i] + sum y[src]) + c   (thread per node)
__global__ void k_sagg(const float* __restrict__ y, const int* __restrict__ ell,
                       const int* __restrict__ cnt_i, const float* __restrict__ n_in,
                       const float* __restrict__ c_out, float* __restrict__ out) {
  int i = blockIdx.x * blockDim.x + threadIdx.x;
  if (i >= N_NODES) return;
  int deg = cnt_i[i];
  if (deg > SLOTS) deg = SLOTS;
  const int* erow = ell + (size_t)i * SLOTS;
  float s = y[i];
  int j = 0;
  for (; j + 8 <= deg; j += 8) {
    int4 a = *(const int4*)(erow + j);
    int4 b = *(const int4*)(erow + j + 4);
    s += y[a.x] + y[a.y] + y[a.z] + y[a.w];
    s += y[b.x] + y[b.y] + y[b.z] + y[b.w];
  }
  for (; j < deg; ++j) s += y[erow[j]];
  out[i] = n_in[i] * s + c_out[0];
}

extern "C" void kernel_launch(void* const* d_in, const int* in_sizes, int n_in_cnt,
                              void* d_out, int out_size, void* d_ws, size_t ws_size,
                              hipStream_t stream) {
  const float* weight = (const float*)d_in[0];
  const int* sig = (const int*)d_in[1];
  const int* src = (const int*)d_in[2];
  const int* dst = (const int*)d_in[3];
  const float* emb = (const float*)d_in[4];
  const float* linW = (const float*)d_in[5];
  const float* linb = (const float*)d_in[6];
  const float* W0 = (const float*)d_in[7];
  const float* b0 = (const float*)d_in[8];
  const float* W1 = (const float*)d_in[9];
  const float* b1 = (const float*)d_in[10];
  const float* W2 = (const float*)d_in[11];
  const float* b2 = (const float*)d_in[12];
  const float* pW = (const float*)d_in[13];
  const float* pb = (const float*)d_in[14];
  float* out = (float*)d_out;

  char* ws = (char*)d_ws;
  size_t off = 0;
  auto alloc = [&](size_t bytes) {
    void* p = ws + off;
    off += (bytes + 255) & ~(size_t)255;
    return p;
  };
  // cnt_o, cnt_i, yv contiguous: one memset zeroes all three
  int* cnt_o = (int*)alloc((size_t)N_NODES * 4);
  int* cnt_i = (int*)alloc((size_t)N_NODES * 4);
  float* yv = (float*)alloc((size_t)N_NODES * 4);
  float* n_out = (float*)alloc((size_t)N_NODES * 4);
  float* n_in = (float*)alloc((size_t)N_NODES * 4);
  int* ell = (int*)alloc((size_t)N_NODES * SLOTS * 4);
  f16* Wt = (f16*)alloc((size_t)2 * DIM * DIM * 2);
  float* wt_vec = (float*)alloc((size_t)DIM * 4);
  float* c_out = (float*)alloc(256);
  f16* B0 = (f16*)alloc((size_t)M_PAD * DIM * 2);
  f16* B1 = (f16*)alloc((size_t)M_PAD * DIM * 2);

  dim3 blk(256);
  hipMemsetAsync(cnt_o, 0, (char*)n_out - (char*)cnt_o, stream);  // cnt_o+cnt_i+yv
  k_setup<<<B_FEAT, blk, 0, stream>>>(src, dst, cnt_o, cnt_i, ell,
                                      W0, W1, Wt, W2, b2, pW, pb, wt_vec, c_out,
                                      weight, sig, emb, linW, linb, B0);
  k_norms<<<(N_NODES + 255) / 256, blk, 0, stream>>>(cnt_o, cnt_i, n_out, n_in);

  dim3 ggrid(DIM / 128, M_PAD / 128);
  // layer 1
  k_spmm<<<N_NODES / 4, blk, 0, stream>>>(B0, B1, ell, cnt_i, n_in, n_out);
  k_gemm<<<ggrid, blk, 0, stream>>>(B1, Wt, b0, n_out, B0, nullptr, nullptr);
  // layer 2 + fused final GEMV (layer-3 collapse)
  k_spmm<<<N_NODES / 4, blk, 0, stream>>>(B0, B1, ell, cnt_i, n_in, n_out);
  k_gemm<<<ggrid, blk, 0, stream>>>(B1, Wt + (size_t)DIM * DIM, b1, n_out, nullptr, wt_vec, yv);
  // layer-3 scalar aggregation
  k_sagg<<<(N_NODES + 255) / 256, blk, 0, stream>>>(yv, ell, cnt_i, n_in, c_out, out);
}